// Round 8
// baseline (130.947 us; speedup 1.0000x reference)
//
#include <hip/hip_runtime.h>
#include <math.h>

#define NROWS 2048
#define KDIM  20000
#define PDIM  32
#define NTILE 1250            // 20000 / 16 column tiles
#define CCH   250             // column chunks
#define TPC   5               // tiles per chunk: 1250 = 250 * 5, contiguous
#define RG    8               // row groups of 256 samples
#define MAINB (RG * CCH)      // 2000 main blocks (~8 per CU)
#define PREPB 313             // ceil(KDIM / 64)
#define PRIORB 64
#define STATS_N (NROWS * 4)

// fancy-path ws layout (bytes)
#define OFF_STATS (KDIM * PDIM * 2)            // betaT: 1,280,000
#define OFF_PRIOR (OFF_STATS + STATS_N * 4)    // stats: +32,768
#define WS_NEEDED (OFF_PRIOR + PREPB * 8)

typedef short bf16x8 __attribute__((ext_vector_type(8)));
typedef unsigned short u16x8 __attribute__((ext_vector_type(8)));
typedef float f32x4  __attribute__((ext_vector_type(4)));
typedef int   i32x4  __attribute__((ext_vector_type(4)));

__device__ __forceinline__ short f2bf(float f) {
  unsigned u = __float_as_uint(f);
  u += 0x7FFF + ((u >> 16) & 1);          // RNE
  return (short)(u >> 16);
}
__device__ __forceinline__ float wredf(float v) {
#pragma unroll
  for (int o = 32; o > 0; o >>= 1) v += __shfl_down(v, o, 64);
  return v;
}
__device__ __forceinline__ double wredd(double v) {
#pragma unroll
  for (int o = 32; o > 0; o >>= 1) v += __shfl_down(v, o, 64);
  return v;
}

// ===================== fancy path =====================

// betaT[k][p] bf16 transpose + Gaussian prior partials + stats zeroing.
__global__ void prep_k(const float* __restrict__ beta, const float* __restrict__ mu,
                       const float* __restrict__ m0p, const float* __restrict__ s0p,
                       unsigned short* __restrict__ betaT,
                       float* __restrict__ stats, double* __restrict__ priorpart)
{
  __shared__ float red[4];
  const int tid = threadIdx.x;
  const int gi = blockIdx.x * 256 + tid;
  if (gi < STATS_N) stats[gi] = 0.0f;

  const int kk = blockIdx.x * 64 + (tid & 63);
  const int pg = tid >> 6;              // p-group 0..3 (8 p's each)
  const float m0 = m0p[0], s0 = s0p[0];
  const float inv2s2 = 0.5f / (s0 * s0);
  const float cnst = -0.5f * logf(6.283185307179586f * s0 * s0);

  float fs = 0.0f;
  if (kk < KDIM) {
    u16x8 w;
#pragma unroll
    for (int i = 0; i < 8; ++i) {
      float v = beta[(pg * 8 + i) * KDIM + kk];
      float d = v - m0;
      fs += cnst - d * d * inv2s2;
      w[i] = (unsigned short)f2bf(v);
    }
    *(u16x8*)(betaT + kk * PDIM + pg * 8) = w;
    if (pg == 0) {
      float d = mu[kk] - m0;
      fs += cnst - d * d * inv2s2;
    }
  }
  fs = wredf(fs);
  if ((tid & 63) == 0) red[tid >> 6] = fs;
  __syncthreads();
  if (tid == 0)
    priorpart[blockIdx.x] =
        (double)red[0] + (double)red[1] + (double)red[2] + (double)red[3];
}

// Main: wave owns 64 samples (4 MFMA fragments); 5 CONTIGUOUS column tiles
// (sequential 64B lines per Y row -> DRAM page locality), depth-2 pipeline,
// fully static, ~8 blocks/CU for latency hiding.
__global__ __launch_bounds__(256, 4) void main_k(
    const float* __restrict__ X, const int* __restrict__ Y,
    const float* __restrict__ mu, const unsigned short* __restrict__ betaT,
    float* __restrict__ stats)
{
  __shared__ float lgt[128];
  const int tid = threadIdx.x;
  if (tid < 128) lgt[tid] = lgammaf((float)tid + 1.0f);
  __syncthreads();

  const int brow = blockIdx.x / CCH;
  const int c    = blockIdx.x % CCH;
  const int wave = tid >> 6;
  const int lane = tid & 63;
  const int lg = lane >> 4;
  const int ln = lane & 15;
  const int sbase = brow * 256 + wave * 64;
  const int t0 = c * TPC;

  // B operands: X rows as bf16, persistent. Fragment F = samples sbase+F*16+ln.
  bf16x8 xb[4];
  int yoff[4];
#pragma unroll
  for (int F = 0; F < 4; ++F) {
    const int s = sbase + F * 16 + ln;
    const float* xp = X + s * PDIM + lg * 8;
    float4 x0 = *(const float4*)xp;
    float4 x1 = *(const float4*)(xp + 4);
    xb[F][0] = f2bf(x0.x); xb[F][1] = f2bf(x0.y);
    xb[F][2] = f2bf(x0.z); xb[F][3] = f2bf(x0.w);
    xb[F][4] = f2bf(x1.x); xb[F][5] = f2bf(x1.y);
    xb[F][6] = f2bf(x1.z); xb[F][7] = f2bf(x1.w);
    yoff[F] = s * KDIM + lg * 4;
  }

  float S[4], SY[4], SYL[4], SLG[4];
#pragma unroll
  for (int F = 0; F < 4; ++F) { S[F] = 0.f; SY[F] = 0.f; SYL[F] = 0.f; SLG[F] = 0.f; }

  const unsigned short* bt = betaT + ln * PDIM + lg * 8;

#define LOADY(slot, t_) do {                                                  \
    const int _o = (t_) * 16;                                                 \
    _Pragma("unroll")                                                         \
    for (int F = 0; F < 4; ++F)                                               \
      slot[F] = *(const i32x4*)(Y + yoff[F] + _o);                            \
  } while (0)
#define LDAF(t_)  (*(const bf16x8*)(bt + (t_) * 16 * PDIM))
#define LDMU(t_)  (*(const float4*)(mu + (t_) * 16 + lg * 4))
#define COMPUTE(ySlot, afv, m4v) do {                                         \
    _Pragma("unroll")                                                         \
    for (int F = 0; F < 4; ++F) {                                             \
      f32x4 cc = { m4v.x, m4v.y, m4v.z, m4v.w };                              \
      cc = __builtin_amdgcn_mfma_f32_16x16x32_bf16(afv, xb[F], cc, 0, 0, 0);  \
      const int yqa[4] = { ySlot[F][0], ySlot[F][1],                          \
                           ySlot[F][2], ySlot[F][3] };                        \
      _Pragma("unroll")                                                       \
      for (int j = 0; j < 4; ++j) {                                           \
        const float logit = cc[j];                                            \
        S[F] += __expf(logit);                                                \
        const float yf = (float)yqa[j];                                       \
        SY[F]  += yf;                                                         \
        SYL[F] = fmaf(yf, logit, SYL[F]);                                     \
        SLG[F] += lgt[yqa[j]];                                                \
      }                                                                       \
    }                                                                         \
  } while (0)

  // 5 contiguous tiles, static depth-2 A/B pipeline.
  i32x4 ya[4], yb[4];
  bf16x8 afA, afB;
  float4 mA, mB;
  LOADY(ya, t0);     afA = LDAF(t0);     mA = LDMU(t0);
  LOADY(yb, t0 + 1); afB = LDAF(t0 + 1); mB = LDMU(t0 + 1);
  COMPUTE(ya, afA, mA);
  LOADY(ya, t0 + 2); afA = LDAF(t0 + 2); mA = LDMU(t0 + 2);
  COMPUTE(yb, afB, mB);
  LOADY(yb, t0 + 3); afB = LDAF(t0 + 3); mB = LDMU(t0 + 3);
  COMPUTE(ya, afA, mA);
  LOADY(ya, t0 + 4); afA = LDAF(t0 + 4); mA = LDMU(t0 + 4);
  COMPUTE(yb, afB, mB);
  COMPUTE(ya, afA, mA);
#undef LOADY
#undef LDAF
#undef LDMU
#undef COMPUTE

#pragma unroll
  for (int F = 0; F < 4; ++F) {
    S[F]   += __shfl_xor(S[F],   16, 64); S[F]   += __shfl_xor(S[F],   32, 64);
    SY[F]  += __shfl_xor(SY[F],  16, 64); SY[F]  += __shfl_xor(SY[F],  32, 64);
    SYL[F] += __shfl_xor(SYL[F], 16, 64); SYL[F] += __shfl_xor(SYL[F], 32, 64);
    SLG[F] += __shfl_xor(SLG[F], 16, 64); SLG[F] += __shfl_xor(SLG[F], 32, 64);
  }
  if (lg == 0) {
#pragma unroll
    for (int F = 0; F < 4; ++F) {
      const int s = sbase + F * 16 + ln;
      atomicAdd(&stats[s * 4 + 0], S[F]);
      atomicAdd(&stats[s * 4 + 1], SY[F]);
      atomicAdd(&stats[s * 4 + 2], SYL[F]);
      atomicAdd(&stats[s * 4 + 3], SLG[F]);
    }
  }
}

__global__ void combine_k(const float* __restrict__ stats,
                          const double* __restrict__ priorpart,
                          float* __restrict__ out)
{
  double part = 0.0;
  for (int r = threadIdx.x; r < NROWS; r += 256) {
    float S   = stats[r * 4 + 0];
    float n   = stats[r * 4 + 1];
    float SYL = stats[r * 4 + 2];
    float SLG = stats[r * 4 + 3];
    part += (double)lgammaf(n + 1.0f) - (double)SLG + (double)SYL
          - (double)n * (double)logf(S);
  }
  for (int i = threadIdx.x; i < PREPB; i += 256) part += priorpart[i];
  part = wredd(part);
  __shared__ double pd[4];
  if ((threadIdx.x & 63) == 0) pd[threadIdx.x >> 6] = part;
  __syncthreads();
  if (threadIdx.x == 0)
    out[0] = (float)(pd[0] + pd[1] + pd[2] + pd[3]);
}

// ===================== fallback path (R3, needs only 32KB ws) =====================

__global__ void fb_init_k(float* stats, double* acc) {
  int i = blockIdx.x * blockDim.x + threadIdx.x;
  if (i < STATS_N) stats[i] = 0.0f;
  if (i == 0) acc[0] = 0.0;
}

__global__ __launch_bounds__(256, 8) void fb_main_k(
    const float* __restrict__ X, const int* __restrict__ Y,
    const float* __restrict__ mu, const float* __restrict__ beta,
    const float* __restrict__ m0p, const float* __restrict__ s0p,
    float* __restrict__ stats, double* __restrict__ acc)
{
  __shared__ float lgt[128];
  __shared__ float red[4];
  const int tid = threadIdx.x;
  const int FB_MAINB = 2048;

  if (blockIdx.x >= FB_MAINB) {
    const int b = blockIdx.x - FB_MAINB;
    const float m0 = m0p[0], s0 = s0p[0];
    const float inv2s2 = 0.5f / (s0 * s0);
    const float cnst = -0.5f * logf(6.283185307179586f * s0 * s0);
    const int total = KDIM + PDIM * KDIM;
    float fs = 0.0f;
    for (int i = b * 256 + tid; i < total; i += PRIORB * 256) {
      float v = (i < KDIM) ? mu[i] : beta[i - KDIM];
      float d = v - m0;
      fs += cnst - d * d * inv2s2;
    }
    fs = wredf(fs);
    if ((tid & 63) == 0) red[tid >> 6] = fs;
    __syncthreads();
    if (tid == 0) {
      double tsum = (double)red[0] + (double)red[1] + (double)red[2] + (double)red[3];
      atomicAdd(acc, tsum);
    }
    return;
  }

  const int brow  = blockIdx.x / 64;
  const int chunk = blockIdx.x % 64;
  const int wave = tid >> 6;
  const int lane = tid & 63;
  const int lg = lane >> 4;
  const int ln = lane & 15;
  const int sample = brow * 64 + wave * 16 + ln;

  if (tid < 128) lgt[tid] = lgammaf((float)tid + 1.0f);
  __syncthreads();

  bf16x8 xb;
  {
    const float* xp = X + sample * PDIM + lg * 8;
    float4 x0 = *(const float4*)xp;
    float4 x1 = *(const float4*)(xp + 4);
    xb[0] = f2bf(x0.x); xb[1] = f2bf(x0.y); xb[2] = f2bf(x0.z); xb[3] = f2bf(x0.w);
    xb[4] = f2bf(x1.x); xb[5] = f2bf(x1.y); xb[6] = f2bf(x1.z); xb[7] = f2bf(x1.w);
  }
  const size_t ybase = (size_t)sample * KDIM + (size_t)lg * 4;
  const float* bcol = beta + lg * 8 * KDIM + ln;

  float S = 0.f, SY = 0.f, SYL = 0.f, SLG = 0.f;
  int t = chunk;
  int4   yv = *(const int4*)(Y + ybase + (size_t)t * 16);
  float4 m4 = *(const float4*)(mu + t * 16 + lg * 4);

  while (t < NTILE) {
    const int col0 = t * 16;
    const int tn = t + 64;
    const int ts = (tn < NTILE) ? tn : t;
    int4   yv_n = *(const int4*)(Y + ybase + (size_t)ts * 16);
    float4 m4_n = *(const float4*)(mu + ts * 16 + lg * 4);
    bf16x8 af;
#pragma unroll
    for (int i = 0; i < 8; ++i) af[i] = f2bf(bcol[i * KDIM + col0]);
    f32x4 c = { m4.x, m4.y, m4.z, m4.w };
    c = __builtin_amdgcn_mfma_f32_16x16x32_bf16(af, xb, c, 0, 0, 0);
    const int ya[4] = { yv.x, yv.y, yv.z, yv.w };
#pragma unroll
    for (int j = 0; j < 4; ++j) {
      const float logit = c[j];
      S += __expf(logit);
      const float yf = (float)ya[j];
      SY  += yf;
      SYL += yf * logit;
      SLG += lgt[ya[j]];
    }
    t = tn; yv = yv_n; m4 = m4_n;
  }

  S   += __shfl_xor(S,   16, 64); S   += __shfl_xor(S,   32, 64);
  SY  += __shfl_xor(SY,  16, 64); SY  += __shfl_xor(SY,  32, 64);
  SYL += __shfl_xor(SYL, 16, 64); SYL += __shfl_xor(SYL, 32, 64);
  SLG += __shfl_xor(SLG, 16, 64); SLG += __shfl_xor(SLG, 32, 64);
  if (lg == 0) {
    atomicAdd(&stats[sample * 4 + 0], S);
    atomicAdd(&stats[sample * 4 + 1], SY);
    atomicAdd(&stats[sample * 4 + 2], SYL);
    atomicAdd(&stats[sample * 4 + 3], SLG);
  }
}

__global__ void fb_combine_k(const float* __restrict__ stats,
                             const double* __restrict__ acc,
                             float* __restrict__ out)
{
  double part = 0.0;
  for (int r = threadIdx.x; r < NROWS; r += 256) {
    float S   = stats[r * 4 + 0];
    float n   = stats[r * 4 + 1];
    float SYL = stats[r * 4 + 2];
    float SLG = stats[r * 4 + 3];
    part += (double)lgammaf(n + 1.0f) - (double)SLG + (double)SYL
          - (double)n * (double)logf(S);
  }
  part = wredd(part);
  __shared__ double pd[4];
  if ((threadIdx.x & 63) == 0) pd[threadIdx.x >> 6] = part;
  __syncthreads();
  if (threadIdx.x == 0)
    out[0] = (float)(pd[0] + pd[1] + pd[2] + pd[3] + acc[0]);
}

extern "C" void kernel_launch(void* const* d_in, const int* in_sizes, int n_in,
                              void* d_out, int out_size, void* d_ws, size_t ws_size,
                              hipStream_t stream) {
  const float* X    = (const float*)d_in[0];
  const int*   Y    = (const int*)d_in[1];
  const float* mu   = (const float*)d_in[2];
  const float* beta = (const float*)d_in[3];
  const float* m0   = (const float*)d_in[4];
  const float* s0   = (const float*)d_in[5];
  float* out = (float*)d_out;

  if (ws_size >= (size_t)WS_NEEDED) {
    unsigned short* betaT = (unsigned short*)d_ws;
    float*  stats = (float*)((char*)d_ws + OFF_STATS);
    double* prior = (double*)((char*)d_ws + OFF_PRIOR);
    prep_k<<<dim3(PREPB), dim3(256), 0, stream>>>(beta, mu, m0, s0, betaT, stats, prior);
    main_k<<<dim3(MAINB), dim3(256), 0, stream>>>(X, Y, mu, betaT, stats);
    combine_k<<<dim3(1), dim3(256), 0, stream>>>(stats, prior, out);
  } else {
    float*  stats = (float*)d_ws;
    double* acc   = (double*)((char*)d_ws + STATS_N * sizeof(float));
    fb_init_k<<<dim3((STATS_N + 255) / 256), dim3(256), 0, stream>>>(stats, acc);
    fb_main_k<<<dim3(2048 + PRIORB), dim3(256), 0, stream>>>(
        X, Y, mu, beta, m0, s0, stats, acc);
    fb_combine_k<<<dim3(1), dim3(256), 0, stream>>>(stats, acc, out);
  }
}

// Round 9
// 47.177 us; speedup vs baseline: 2.7757x; 2.7757x over previous
//
#include <hip/hip_runtime.h>
#include <math.h>

#define NROWS 2048
#define KDIM  20000
#define PDIM  32
#define CHW   80              // chunk width (cols): 250 chunks * 80 = 20000
#define NCH   250
#define SLOTS 20              // int4 slots per row per chunk
#define PADW  84              // padded LDS row stride (words): 2-way banks, 16B aligned
#define KSL   24              // k-slices: 10 slices of 11 chunks + 14 of 10
#define RGRP  32              // row groups of 64 samples
#define MAINB (RGRP * KSL)    // 768 blocks = exactly 3 per CU
#define PREPB 313             // ceil(KDIM / 64)
#define PRIORB 64
#define STATS_N (NROWS * 4)

// fancy-path ws layout (bytes)
#define OFF_STATS (KDIM * PDIM * 2)            // betaT: 1,280,000
#define OFF_PRIOR (OFF_STATS + STATS_N * 4)    // stats: +32,768
#define WS_NEEDED (OFF_PRIOR + PREPB * 8)

typedef short bf16x8 __attribute__((ext_vector_type(8)));
typedef unsigned short u16x8 __attribute__((ext_vector_type(8)));
typedef float f32x4  __attribute__((ext_vector_type(4)));
typedef int   i32x4  __attribute__((ext_vector_type(4)));

__device__ __forceinline__ short f2bf(float f) {
  unsigned u = __float_as_uint(f);
  u += 0x7FFF + ((u >> 16) & 1);          // RNE
  return (short)(u >> 16);
}
__device__ __forceinline__ float wredf(float v) {
#pragma unroll
  for (int o = 32; o > 0; o >>= 1) v += __shfl_down(v, o, 64);
  return v;
}
__device__ __forceinline__ double wredd(double v) {
#pragma unroll
  for (int o = 32; o > 0; o >>= 1) v += __shfl_down(v, o, 64);
  return v;
}

// ===================== fancy path =====================

// betaT[k][p] bf16 transpose + Gaussian prior partials + stats zeroing.
__global__ void prep_k(const float* __restrict__ beta, const float* __restrict__ mu,
                       const float* __restrict__ m0p, const float* __restrict__ s0p,
                       unsigned short* __restrict__ betaT,
                       float* __restrict__ stats, double* __restrict__ priorpart)
{
  __shared__ float red[4];
  const int tid = threadIdx.x;
  const int gi = blockIdx.x * 256 + tid;
  if (gi < STATS_N) stats[gi] = 0.0f;

  const int kk = blockIdx.x * 64 + (tid & 63);
  const int pg = tid >> 6;              // p-group 0..3 (8 p's each)
  const float m0 = m0p[0], s0 = s0p[0];
  const float inv2s2 = 0.5f / (s0 * s0);
  const float cnst = -0.5f * logf(6.283185307179586f * s0 * s0);

  float fs = 0.0f;
  if (kk < KDIM) {
    u16x8 w;
#pragma unroll
    for (int i = 0; i < 8; ++i) {
      float v = beta[(pg * 8 + i) * KDIM + kk];
      float d = v - m0;
      fs += cnst - d * d * inv2s2;
      w[i] = (unsigned short)f2bf(v);
    }
    *(u16x8*)(betaT + kk * PDIM + pg * 8) = w;
    if (pg == 0) {
      float d = mu[kk] - m0;
      fs += cnst - d * d * inv2s2;
    }
  }
  fs = wredf(fs);
  if ((tid & 63) == 0) red[tid >> 6] = fs;
  __syncthreads();
  if (tid == 0)
    priorpart[blockIdx.x] =
        (double)red[0] + (double)red[1] + (double)red[2] + (double)red[3];
}

// Main: block owns 64 samples; Y streamed through LDS in [64 x 80] chunks.
// Staging loads are lane-sequential (2 contiguous 512B row-segments per
// instruction — the fill-kernel pattern). Double-buffered LDS, async-STAGE
// split (gload early -> regs, ds_write after barrier). Wave w computes
// MFMA fragment F=w (16 samples). 768 blocks = exactly 3/CU.
__global__ __launch_bounds__(256, 3) void main_k(
    const float* __restrict__ X, const int* __restrict__ Y,
    const float* __restrict__ mu, const unsigned short* __restrict__ betaT,
    float* __restrict__ stats)
{
  __shared__ float lgt[128];
  __shared__ int ybuf[2][64 * PADW];   // 2 x 21504 B
  const int tid = threadIdx.x;
  if (tid < 128) lgt[tid] = lgammaf((float)tid + 1.0f);

  const int rg = blockIdx.x / KSL;
  const int ks = blockIdx.x % KSL;
  const int sbase = rg * 64;
  const int cstart = (ks < 10) ? ks * 11 : 110 + (ks - 10) * 10;
  const int cps    = (ks < 10) ? 11 : 10;

  const int wave = tid >> 6, lane = tid & 63;
  const int lg = lane >> 4, ln = lane & 15;

  // staging geometry: flat = i*256+tid over [64 rows][20 slots]; constant/thread
  int goff[5], loff[5];
#pragma unroll
  for (int i = 0; i < 5; ++i) {
    const int flat = i * 256 + tid;       // 0..1279
    const int row = flat / SLOTS, slot = flat % SLOTS;
    goff[i] = (sbase + row) * KDIM + slot * 4;
    loff[i] = row * PADW + slot * 4;
  }

  // X fragment: wave w's 16 samples (B operand; A=betaT, D[i][j]=logit[col i][samp j])
  const int samp = sbase + wave * 16 + ln;
  bf16x8 xb;
  {
    const float* xp = X + samp * PDIM + lg * 8;
    float4 x0 = *(const float4*)xp;
    float4 x1 = *(const float4*)(xp + 4);
    xb[0] = f2bf(x0.x); xb[1] = f2bf(x0.y); xb[2] = f2bf(x0.z); xb[3] = f2bf(x0.w);
    xb[4] = f2bf(x1.x); xb[5] = f2bf(x1.y); xb[6] = f2bf(x1.z); xb[7] = f2bf(x1.w);
  }

  float S = 0.f, SY = 0.f, SYL = 0.f, SLG = 0.f;

#define GLOAD(c_) do { const int _cb = (c_) * CHW;                            \
    r0 = *(const i32x4*)(Y + goff[0] + _cb);                                  \
    r1 = *(const i32x4*)(Y + goff[1] + _cb);                                  \
    r2 = *(const i32x4*)(Y + goff[2] + _cb);                                  \
    r3 = *(const i32x4*)(Y + goff[3] + _cb);                                  \
    r4 = *(const i32x4*)(Y + goff[4] + _cb);                                  \
  } while (0)
#define DSW(b_) do {                                                          \
    *(i32x4*)&ybuf[b_][loff[0]] = r0;                                         \
    *(i32x4*)&ybuf[b_][loff[1]] = r1;                                         \
    *(i32x4*)&ybuf[b_][loff[2]] = r2;                                         \
    *(i32x4*)&ybuf[b_][loff[3]] = r3;                                         \
    *(i32x4*)&ybuf[b_][loff[4]] = r4;                                         \
  } while (0)

  i32x4 r0, r1, r2, r3, r4;
  GLOAD(cstart);
  DSW(0);                       // compiler inserts vmcnt before the writes
  GLOAD(cstart + 1);
  __syncthreads();              // buf0 + lgt visible

  const int ybase = wave * 16 + ln;   // this lane's LDS row

  for (int ch = 0; ch < cps; ++ch) {
    const int cur = ch & 1;
    const int cbase = (cstart + ch) * CHW;
#pragma unroll
    for (int tt = 0; tt < 5; ++tt) {
      i32x4 yv = *(const i32x4*)&ybuf[cur][ybase * PADW + (tt * 4 + lg) * 4];
      bf16x8 af = *(const bf16x8*)(betaT + (cbase + tt * 16 + ln) * PDIM + lg * 8);
      float4 m4 = *(const float4*)(mu + cbase + tt * 16 + lg * 4);
      f32x4 cc = { m4.x, m4.y, m4.z, m4.w };
      cc = __builtin_amdgcn_mfma_f32_16x16x32_bf16(af, xb, cc, 0, 0, 0);
      const int ya[4] = { yv[0], yv[1], yv[2], yv[3] };
#pragma unroll
      for (int j = 0; j < 4; ++j) {
        const float logit = cc[j];
        S += __expf(logit);
        const float yf = (float)ya[j];
        SY += yf;
        SYL = fmaf(yf, logit, SYL);
        SLG += lgt[ya[j]];
      }
    }
    __syncthreads();            // all waves done reading buf[cur^1]'s successor slot
    if (ch + 1 < cps) {
      DSW(cur ^ 1);             // write chunk ch+1 (gloaded one iter ago)
      if (ch + 2 < cps) GLOAD(cstart + ch + 2);
    }
    __syncthreads();            // writes visible before next compute
  }
#undef GLOAD
#undef DSW

  // combine the 4 lg partials of each sample (lanes ln, ln+16, ln+32, ln+48)
  S   += __shfl_xor(S,   16, 64); S   += __shfl_xor(S,   32, 64);
  SY  += __shfl_xor(SY,  16, 64); SY  += __shfl_xor(SY,  32, 64);
  SYL += __shfl_xor(SYL, 16, 64); SYL += __shfl_xor(SYL, 32, 64);
  SLG += __shfl_xor(SLG, 16, 64); SLG += __shfl_xor(SLG, 32, 64);
  if (lg == 0) {
    atomicAdd(&stats[samp * 4 + 0], S);
    atomicAdd(&stats[samp * 4 + 1], SY);
    atomicAdd(&stats[samp * 4 + 2], SYL);
    atomicAdd(&stats[samp * 4 + 3], SLG);
  }
}

__global__ void combine_k(const float* __restrict__ stats,
                          const double* __restrict__ priorpart,
                          float* __restrict__ out)
{
  double part = 0.0;
  for (int r = threadIdx.x; r < NROWS; r += 256) {
    float S   = stats[r * 4 + 0];
    float n   = stats[r * 4 + 1];
    float SYL = stats[r * 4 + 2];
    float SLG = stats[r * 4 + 3];
    part += (double)lgammaf(n + 1.0f) - (double)SLG + (double)SYL
          - (double)n * (double)logf(S);
  }
  for (int i = threadIdx.x; i < PREPB; i += 256) part += priorpart[i];
  part = wredd(part);
  __shared__ double pd[4];
  if ((threadIdx.x & 63) == 0) pd[threadIdx.x >> 6] = part;
  __syncthreads();
  if (threadIdx.x == 0)
    out[0] = (float)(pd[0] + pd[1] + pd[2] + pd[3]);
}

// ===================== fallback path (R3, needs only 32KB ws) =====================

__global__ void fb_init_k(float* stats, double* acc) {
  int i = blockIdx.x * blockDim.x + threadIdx.x;
  if (i < STATS_N) stats[i] = 0.0f;
  if (i == 0) acc[0] = 0.0;
}

__global__ __launch_bounds__(256, 8) void fb_main_k(
    const float* __restrict__ X, const int* __restrict__ Y,
    const float* __restrict__ mu, const float* __restrict__ beta,
    const float* __restrict__ m0p, const float* __restrict__ s0p,
    float* __restrict__ stats, double* __restrict__ acc)
{
  __shared__ float lgt[128];
  __shared__ float red[4];
  const int tid = threadIdx.x;
  const int FB_MAINB = 2048;

  if (blockIdx.x >= FB_MAINB) {
    const int b = blockIdx.x - FB_MAINB;
    const float m0 = m0p[0], s0 = s0p[0];
    const float inv2s2 = 0.5f / (s0 * s0);
    const float cnst = -0.5f * logf(6.283185307179586f * s0 * s0);
    const int total = KDIM + PDIM * KDIM;
    float fs = 0.0f;
    for (int i = b * 256 + tid; i < total; i += PRIORB * 256) {
      float v = (i < KDIM) ? mu[i] : beta[i - KDIM];
      float d = v - m0;
      fs += cnst - d * d * inv2s2;
    }
    fs = wredf(fs);
    if ((tid & 63) == 0) red[tid >> 6] = fs;
    __syncthreads();
    if (tid == 0) {
      double tsum = (double)red[0] + (double)red[1] + (double)red[2] + (double)red[3];
      atomicAdd(acc, tsum);
    }
    return;
  }

  const int brow  = blockIdx.x / 64;
  const int chunk = blockIdx.x % 64;
  const int wave = tid >> 6;
  const int lane = tid & 63;
  const int lg = lane >> 4;
  const int ln = lane & 15;
  const int sample = brow * 64 + wave * 16 + ln;

  if (tid < 128) lgt[tid] = lgammaf((float)tid + 1.0f);
  __syncthreads();

  bf16x8 xb;
  {
    const float* xp = X + sample * PDIM + lg * 8;
    float4 x0 = *(const float4*)xp;
    float4 x1 = *(const float4*)(xp + 4);
    xb[0] = f2bf(x0.x); xb[1] = f2bf(x0.y); xb[2] = f2bf(x0.z); xb[3] = f2bf(x0.w);
    xb[4] = f2bf(x1.x); xb[5] = f2bf(x1.y); xb[6] = f2bf(x1.z); xb[7] = f2bf(x1.w);
  }
  const size_t ybase = (size_t)sample * KDIM + (size_t)lg * 4;
  const float* bcol = beta + lg * 8 * KDIM + ln;

  float S = 0.f, SY = 0.f, SYL = 0.f, SLG = 0.f;
  int t = chunk;
  const int FB_NTILE = 1250;
  int4   yv = *(const int4*)(Y + ybase + (size_t)t * 16);
  float4 m4 = *(const float4*)(mu + t * 16 + lg * 4);

  while (t < FB_NTILE) {
    const int col0 = t * 16;
    const int tn = t + 64;
    const int ts = (tn < FB_NTILE) ? tn : t;
    int4   yv_n = *(const int4*)(Y + ybase + (size_t)ts * 16);
    float4 m4_n = *(const float4*)(mu + ts * 16 + lg * 4);
    bf16x8 af;
#pragma unroll
    for (int i = 0; i < 8; ++i) af[i] = f2bf(bcol[i * KDIM + col0]);
    f32x4 c = { m4.x, m4.y, m4.z, m4.w };
    c = __builtin_amdgcn_mfma_f32_16x16x32_bf16(af, xb, c, 0, 0, 0);
    const int ya[4] = { yv.x, yv.y, yv.z, yv.w };
#pragma unroll
    for (int j = 0; j < 4; ++j) {
      const float logit = c[j];
      S += __expf(logit);
      const float yf = (float)ya[j];
      SY  += yf;
      SYL += yf * logit;
      SLG += lgt[ya[j]];
    }
    t = tn; yv = yv_n; m4 = m4_n;
  }

  S   += __shfl_xor(S,   16, 64); S   += __shfl_xor(S,   32, 64);
  SY  += __shfl_xor(SY,  16, 64); SY  += __shfl_xor(SY,  32, 64);
  SYL += __shfl_xor(SYL, 16, 64); SYL += __shfl_xor(SYL, 32, 64);
  SLG += __shfl_xor(SLG, 16, 64); SLG += __shfl_xor(SLG, 32, 64);
  if (lg == 0) {
    atomicAdd(&stats[sample * 4 + 0], S);
    atomicAdd(&stats[sample * 4 + 1], SY);
    atomicAdd(&stats[sample * 4 + 2], SYL);
    atomicAdd(&stats[sample * 4 + 3], SLG);
  }
}

__global__ void fb_combine_k(const float* __restrict__ stats,
                             const double* __restrict__ acc,
                             float* __restrict__ out)
{
  double part = 0.0;
  for (int r = threadIdx.x; r < NROWS; r += 256) {
    float S   = stats[r * 4 + 0];
    float n   = stats[r * 4 + 1];
    float SYL = stats[r * 4 + 2];
    float SLG = stats[r * 4 + 3];
    part += (double)lgammaf(n + 1.0f) - (double)SLG + (double)SYL
          - (double)n * (double)logf(S);
  }
  part = wredd(part);
  __shared__ double pd[4];
  if ((threadIdx.x & 63) == 0) pd[threadIdx.x >> 6] = part;
  __syncthreads();
  if (threadIdx.x == 0)
    out[0] = (float)(pd[0] + pd[1] + pd[2] + pd[3] + acc[0]);
}

extern "C" void kernel_launch(void* const* d_in, const int* in_sizes, int n_in,
                              void* d_out, int out_size, void* d_ws, size_t ws_size,
                              hipStream_t stream) {
  const float* X    = (const float*)d_in[0];
  const int*   Y    = (const int*)d_in[1];
  const float* mu   = (const float*)d_in[2];
  const float* beta = (const float*)d_in[3];
  const float* m0   = (const float*)d_in[4];
  const float* s0   = (const float*)d_in[5];
  float* out = (float*)d_out;

  if (ws_size >= (size_t)WS_NEEDED) {
    unsigned short* betaT = (unsigned short*)d_ws;
    float*  stats = (float*)((char*)d_ws + OFF_STATS);
    double* prior = (double*)((char*)d_ws + OFF_PRIOR);
    prep_k<<<dim3(PREPB), dim3(256), 0, stream>>>(beta, mu, m0, s0, betaT, stats, prior);
    main_k<<<dim3(MAINB), dim3(256), 0, stream>>>(X, Y, mu, betaT, stats);
    combine_k<<<dim3(1), dim3(256), 0, stream>>>(stats, prior, out);
  } else {
    float*  stats = (float*)d_ws;
    double* acc   = (double*)((char*)d_ws + STATS_N * sizeof(float));
    fb_init_k<<<dim3((STATS_N + 255) / 256), dim3(256), 0, stream>>>(stats, acc);
    fb_main_k<<<dim3(2048 + PRIORB), dim3(256), 0, stream>>>(
        X, Y, mu, beta, m0, s0, stats, acc);
    fb_combine_k<<<dim3(1), dim3(256), 0, stream>>>(stats, acc, out);
  }
}

// Round 10
// 44.790 us; speedup vs baseline: 2.9235x; 1.0533x over previous
//
#include <hip/hip_runtime.h>
#include <math.h>

#define NROWS 2048
#define KDIM  20000
#define PDIM  32
#define CHW   80              // chunk width (cols): 250 chunks * 80 = 20000
#define SLOTS 20              // int4 slots per row per chunk
#define PADW  84              // padded LDS row stride (words): 2-way banks only
#define KSL   24              // k-slices: 10 slices of 11 chunks + 14 of 10
#define RGRP  32              // row groups of 64 samples
#define MAINB (RGRP * KSL)    // 768 blocks = exactly 3 per CU
#define PREPB 313             // ceil(KDIM / 64)
#define PRIORB 64
#define STATS_N (NROWS * 4)

// fancy-path ws layout (bytes)
#define OFF_STATS (KDIM * PDIM * 2)            // betaT: 1,280,000
#define OFF_PRIOR (OFF_STATS + STATS_N * 4)    // stats: +32,768
#define WS_NEEDED (OFF_PRIOR + PREPB * 8)

typedef short bf16x8 __attribute__((ext_vector_type(8)));
typedef unsigned short u16x8 __attribute__((ext_vector_type(8)));
typedef float f32x4  __attribute__((ext_vector_type(4)));
typedef int   i32x4  __attribute__((ext_vector_type(4)));

__device__ __forceinline__ short f2bf(float f) {
  unsigned u = __float_as_uint(f);
  u += 0x7FFF + ((u >> 16) & 1);          // RNE
  return (short)(u >> 16);
}
__device__ __forceinline__ float wredf(float v) {
#pragma unroll
  for (int o = 32; o > 0; o >>= 1) v += __shfl_down(v, o, 64);
  return v;
}
__device__ __forceinline__ double wredd(double v) {
#pragma unroll
  for (int o = 32; o > 0; o >>= 1) v += __shfl_down(v, o, 64);
  return v;
}

// ===================== fancy path =====================

// betaT[k][p] bf16 transpose + Gaussian prior partials + stats zeroing.
__global__ void prep_k(const float* __restrict__ beta, const float* __restrict__ mu,
                       const float* __restrict__ m0p, const float* __restrict__ s0p,
                       unsigned short* __restrict__ betaT,
                       float* __restrict__ stats, double* __restrict__ priorpart)
{
  __shared__ float red[4];
  const int tid = threadIdx.x;
  const int gi = blockIdx.x * 256 + tid;
  if (gi < STATS_N) stats[gi] = 0.0f;

  const int kk = blockIdx.x * 64 + (tid & 63);
  const int pg = tid >> 6;              // p-group 0..3 (8 p's each)
  const float m0 = m0p[0], s0 = s0p[0];
  const float inv2s2 = 0.5f / (s0 * s0);
  const float cnst = -0.5f * logf(6.283185307179586f * s0 * s0);

  float fs = 0.0f;
  if (kk < KDIM) {
    u16x8 w;
#pragma unroll
    for (int i = 0; i < 8; ++i) {
      float v = beta[(pg * 8 + i) * KDIM + kk];
      float d = v - m0;
      fs += cnst - d * d * inv2s2;
      w[i] = (unsigned short)f2bf(v);
    }
    *(u16x8*)(betaT + kk * PDIM + pg * 8) = w;
    if (pg == 0) {
      float d = mu[kk] - m0;
      fs += cnst - d * d * inv2s2;
    }
  }
  fs = wredf(fs);
  if ((tid & 63) == 0) red[tid >> 6] = fs;
  __syncthreads();
  if (tid == 0)
    priorpart[blockIdx.x] =
        (double)red[0] + (double)red[1] + (double)red[2] + (double)red[3];
}

// Main: block owns 64 samples; Y streamed through LDS in [64 x 80] chunks.
// WAVE-PRIVATE staging: wave w stages exactly the 16 LDS rows it computes
// (rows w*16..w*16+15), so NO block barriers in the main loop — each wave
// free-runs on its own vmcnt/lgkmcnt deps. Double-buffered, chunk-ahead
// global prefetch. 768 blocks = exactly 3/CU (LDS 43.5 KB).
__global__ __launch_bounds__(256, 3) void main_k(
    const float* __restrict__ X, const int* __restrict__ Y,
    const float* __restrict__ mu, const unsigned short* __restrict__ betaT,
    float* __restrict__ stats)
{
  __shared__ float lgt[128];
  __shared__ int ybuf[2][64 * PADW];   // 2 x 21504 B
  const int tid = threadIdx.x;
  if (tid < 128) lgt[tid] = lgammaf((float)tid + 1.0f);

  const int rg = blockIdx.x / KSL;
  const int ks = blockIdx.x % KSL;
  const int sbase = rg * 64;
  const int cstart = (ks < 10) ? ks * 11 : 110 + (ks - 10) * 10;
  const int cps    = (ks < 10) ? 11 : 10;

  const int wave = tid >> 6, lane = tid & 63;
  const int lg = lane >> 4, ln = lane & 15;

  // staging geometry: wave w owns rows [w*16, w*16+16) x [20 slots]
  int goff[5], loff[5];
#pragma unroll
  for (int i = 0; i < 5; ++i) {
    const int flat = i * 64 + lane;       // 0..319 within this wave's 16 rows
    const int rowl = flat / SLOTS, slot = flat % SLOTS;
    const int row = wave * 16 + rowl;
    goff[i] = (sbase + row) * KDIM + slot * 4;
    loff[i] = row * PADW + slot * 4;
  }

  // X fragment: wave w's 16 samples (B operand; A=betaT, D[i][j]=logit[col i][samp j])
  const int samp = sbase + wave * 16 + ln;
  bf16x8 xb;
  {
    const float* xp = X + samp * PDIM + lg * 8;
    float4 x0 = *(const float4*)xp;
    float4 x1 = *(const float4*)(xp + 4);
    xb[0] = f2bf(x0.x); xb[1] = f2bf(x0.y); xb[2] = f2bf(x0.z); xb[3] = f2bf(x0.w);
    xb[4] = f2bf(x1.x); xb[5] = f2bf(x1.y); xb[6] = f2bf(x1.z); xb[7] = f2bf(x1.w);
  }

  float S = 0.f, SY = 0.f, SYL = 0.f, SLG = 0.f;

#define GLOAD(c_) do { const int _cb = (c_) * CHW;                            \
    r0 = *(const i32x4*)(Y + goff[0] + _cb);                                  \
    r1 = *(const i32x4*)(Y + goff[1] + _cb);                                  \
    r2 = *(const i32x4*)(Y + goff[2] + _cb);                                  \
    r3 = *(const i32x4*)(Y + goff[3] + _cb);                                  \
    r4 = *(const i32x4*)(Y + goff[4] + _cb);                                  \
  } while (0)
#define DSW(b_) do {                                                          \
    *(i32x4*)&ybuf[b_][loff[0]] = r0;                                         \
    *(i32x4*)&ybuf[b_][loff[1]] = r1;                                         \
    *(i32x4*)&ybuf[b_][loff[2]] = r2;                                         \
    *(i32x4*)&ybuf[b_][loff[3]] = r3;                                         \
    *(i32x4*)&ybuf[b_][loff[4]] = r4;                                         \
  } while (0)

  i32x4 r0, r1, r2, r3, r4;
  GLOAD(cstart);
  DSW(0);
  GLOAD(cstart + 1);
  __syncthreads();              // lgt visible (only barrier in the kernel)

  const int ybase = wave * 16 + ln;   // this lane's LDS row (wave-private)

  for (int ch = 0; ch < cps; ++ch) {
    const int cur = ch & 1;
    const int cbase = (cstart + ch) * CHW;
#pragma unroll
    for (int tt = 0; tt < 5; ++tt) {
      i32x4 yv = *(const i32x4*)&ybuf[cur][ybase * PADW + (tt * 4 + lg) * 4];
      bf16x8 af = *(const bf16x8*)(betaT + (cbase + tt * 16 + ln) * PDIM + lg * 8);
      float4 m4 = *(const float4*)(mu + cbase + tt * 16 + lg * 4);
      f32x4 cc = { m4.x, m4.y, m4.z, m4.w };
      cc = __builtin_amdgcn_mfma_f32_16x16x32_bf16(af, xb, cc, 0, 0, 0);
      const int ya[4] = { yv[0], yv[1], yv[2], yv[3] };
#pragma unroll
      for (int j = 0; j < 4; ++j) {
        const float logit = cc[j];
        S += __expf(logit);
        const float yf = (float)ya[j];
        SY += yf;
        SYL = fmaf(yf, logit, SYL);
        SLG += lgt[ya[j]];
      }
    }
    if (ch + 1 < cps) {
      DSW(cur ^ 1);             // waits (per-wave) on GLOAD(ch+1)
      if (ch + 2 < cps) GLOAD(cstart + ch + 2);
    }
  }
#undef GLOAD
#undef DSW

  // combine the 4 lg partials of each sample (lanes ln, ln+16, ln+32, ln+48)
  S   += __shfl_xor(S,   16, 64); S   += __shfl_xor(S,   32, 64);
  SY  += __shfl_xor(SY,  16, 64); SY  += __shfl_xor(SY,  32, 64);
  SYL += __shfl_xor(SYL, 16, 64); SYL += __shfl_xor(SYL, 32, 64);
  SLG += __shfl_xor(SLG, 16, 64); SLG += __shfl_xor(SLG, 32, 64);
  if (lg == 0) {
    atomicAdd(&stats[samp * 4 + 0], S);
    atomicAdd(&stats[samp * 4 + 1], SY);
    atomicAdd(&stats[samp * 4 + 2], SYL);
    atomicAdd(&stats[samp * 4 + 3], SLG);
  }
}

__global__ void combine_k(const float* __restrict__ stats,
                          const double* __restrict__ priorpart,
                          float* __restrict__ out)
{
  double part = 0.0;
  for (int r = threadIdx.x; r < NROWS; r += 256) {
    float S   = stats[r * 4 + 0];
    float n   = stats[r * 4 + 1];
    float SYL = stats[r * 4 + 2];
    float SLG = stats[r * 4 + 3];
    part += (double)lgammaf(n + 1.0f) - (double)SLG + (double)SYL
          - (double)n * (double)logf(S);
  }
  for (int i = threadIdx.x; i < PREPB; i += 256) part += priorpart[i];
  part = wredd(part);
  __shared__ double pd[4];
  if ((threadIdx.x & 63) == 0) pd[threadIdx.x >> 6] = part;
  __syncthreads();
  if (threadIdx.x == 0)
    out[0] = (float)(pd[0] + pd[1] + pd[2] + pd[3]);
}

// ===================== fallback path (R3, needs only 32KB ws) =====================

__global__ void fb_init_k(float* stats, double* acc) {
  int i = blockIdx.x * blockDim.x + threadIdx.x;
  if (i < STATS_N) stats[i] = 0.0f;
  if (i == 0) acc[0] = 0.0;
}

__global__ __launch_bounds__(256, 8) void fb_main_k(
    const float* __restrict__ X, const int* __restrict__ Y,
    const float* __restrict__ mu, const float* __restrict__ beta,
    const float* __restrict__ m0p, const float* __restrict__ s0p,
    float* __restrict__ stats, double* __restrict__ acc)
{
  __shared__ float lgt[128];
  __shared__ float red[4];
  const int tid = threadIdx.x;
  const int FB_MAINB = 2048;

  if (blockIdx.x >= FB_MAINB) {
    const int b = blockIdx.x - FB_MAINB;
    const float m0 = m0p[0], s0 = s0p[0];
    const float inv2s2 = 0.5f / (s0 * s0);
    const float cnst = -0.5f * logf(6.283185307179586f * s0 * s0);
    const int total = KDIM + PDIM * KDIM;
    float fs = 0.0f;
    for (int i = b * 256 + tid; i < total; i += PRIORB * 256) {
      float v = (i < KDIM) ? mu[i] : beta[i - KDIM];
      float d = v - m0;
      fs += cnst - d * d * inv2s2;
    }
    fs = wredf(fs);
    if ((tid & 63) == 0) red[tid >> 6] = fs;
    __syncthreads();
    if (tid == 0) {
      double tsum = (double)red[0] + (double)red[1] + (double)red[2] + (double)red[3];
      atomicAdd(acc, tsum);
    }
    return;
  }

  const int brow  = blockIdx.x / 64;
  const int chunk = blockIdx.x % 64;
  const int wave = tid >> 6;
  const int lane = tid & 63;
  const int lg = lane >> 4;
  const int ln = lane & 15;
  const int sample = brow * 64 + wave * 16 + ln;

  if (tid < 128) lgt[tid] = lgammaf((float)tid + 1.0f);
  __syncthreads();

  bf16x8 xb;
  {
    const float* xp = X + sample * PDIM + lg * 8;
    float4 x0 = *(const float4*)xp;
    float4 x1 = *(const float4*)(xp + 4);
    xb[0] = f2bf(x0.x); xb[1] = f2bf(x0.y); xb[2] = f2bf(x0.z); xb[3] = f2bf(x0.w);
    xb[4] = f2bf(x1.x); xb[5] = f2bf(x1.y); xb[6] = f2bf(x1.z); xb[7] = f2bf(x1.w);
  }
  const size_t ybase = (size_t)sample * KDIM + (size_t)lg * 4;
  const float* bcol = beta + lg * 8 * KDIM + ln;

  float S = 0.f, SY = 0.f, SYL = 0.f, SLG = 0.f;
  int t = chunk;
  const int FB_NTILE = 1250;
  int4   yv = *(const int4*)(Y + ybase + (size_t)t * 16);
  float4 m4 = *(const float4*)(mu + t * 16 + lg * 4);

  while (t < FB_NTILE) {
    const int col0 = t * 16;
    const int tn = t + 64;
    const int ts = (tn < FB_NTILE) ? tn : t;
    int4   yv_n = *(const int4*)(Y + ybase + (size_t)ts * 16);
    float4 m4_n = *(const float4*)(mu + ts * 16 + lg * 4);
    bf16x8 af;
#pragma unroll
    for (int i = 0; i < 8; ++i) af[i] = f2bf(bcol[i * KDIM + col0]);
    f32x4 c = { m4.x, m4.y, m4.z, m4.w };
    c = __builtin_amdgcn_mfma_f32_16x16x32_bf16(af, xb, c, 0, 0, 0);
    const int ya[4] = { yv.x, yv.y, yv.z, yv.w };
#pragma unroll
    for (int j = 0; j < 4; ++j) {
      const float logit = c[j];
      S += __expf(logit);
      const float yf = (float)ya[j];
      SY  += yf;
      SYL += yf * logit;
      SLG += lgt[ya[j]];
    }
    t = tn; yv = yv_n; m4 = m4_n;
  }

  S   += __shfl_xor(S,   16, 64); S   += __shfl_xor(S,   32, 64);
  SY  += __shfl_xor(SY,  16, 64); SY  += __shfl_xor(SY,  32, 64);
  SYL += __shfl_xor(SYL, 16, 64); SYL += __shfl_xor(SYL, 32, 64);
  SLG += __shfl_xor(SLG, 16, 64); SLG += __shfl_xor(SLG, 32, 64);
  if (lg == 0) {
    atomicAdd(&stats[sample * 4 + 0], S);
    atomicAdd(&stats[sample * 4 + 1], SY);
    atomicAdd(&stats[sample * 4 + 2], SYL);
    atomicAdd(&stats[sample * 4 + 3], SLG);
  }
}

__global__ void fb_combine_k(const float* __restrict__ stats,
                             const double* __restrict__ acc,
                             float* __restrict__ out)
{
  double part = 0.0;
  for (int r = threadIdx.x; r < NROWS; r += 256) {
    float S   = stats[r * 4 + 0];
    float n   = stats[r * 4 + 1];
    float SYL = stats[r * 4 + 2];
    float SLG = stats[r * 4 + 3];
    part += (double)lgammaf(n + 1.0f) - (double)SLG + (double)SYL
          - (double)n * (double)logf(S);
  }
  part = wredd(part);
  __shared__ double pd[4];
  if ((threadIdx.x & 63) == 0) pd[threadIdx.x >> 6] = part;
  __syncthreads();
  if (threadIdx.x == 0)
    out[0] = (float)(pd[0] + pd[1] + pd[2] + pd[3] + acc[0]);
}

extern "C" void kernel_launch(void* const* d_in, const int* in_sizes, int n_in,
                              void* d_out, int out_size, void* d_ws, size_t ws_size,
                              hipStream_t stream) {
  const float* X    = (const float*)d_in[0];
  const int*   Y    = (const int*)d_in[1];
  const float* mu   = (const float*)d_in[2];
  const float* beta = (const float*)d_in[3];
  const float* m0   = (const float*)d_in[4];
  const float* s0   = (const float*)d_in[5];
  float* out = (float*)d_out;

  if (ws_size >= (size_t)WS_NEEDED) {
    unsigned short* betaT = (unsigned short*)d_ws;
    float*  stats = (float*)((char*)d_ws + OFF_STATS);
    double* prior = (double*)((char*)d_ws + OFF_PRIOR);
    prep_k<<<dim3(PREPB), dim3(256), 0, stream>>>(beta, mu, m0, s0, betaT, stats, prior);
    main_k<<<dim3(MAINB), dim3(256), 0, stream>>>(X, Y, mu, betaT, stats);
    combine_k<<<dim3(1), dim3(256), 0, stream>>>(stats, prior, out);
  } else {
    float*  stats = (float*)d_ws;
    double* acc   = (double*)((char*)d_ws + STATS_N * sizeof(float));
    fb_init_k<<<dim3((STATS_N + 255) / 256), dim3(256), 0, stream>>>(stats, acc);
    fb_main_k<<<dim3(2048 + PRIORB), dim3(256), 0, stream>>>(
        X, Y, mu, beta, m0, s0, stats, acc);
    fb_combine_k<<<dim3(1), dim3(256), 0, stream>>>(stats, acc, out);
  }
}